// Round 1
// 86.373 us; speedup vs baseline: 1.1249x; 1.1249x over previous
//
#include <hip/hip_runtime.h>
#include <hip/hip_bf16.h>

// ---------------------------------------------------------------------------
// CMHSAttn v14: fp32 in/out.
//  - combine kernel DELETED: attn blocks are 512 threads (8 waves) covering
//    64 q rows of one head; waves split the 4096 keys 8-ways (8 kt each, same
//    per-wave work as v13) and reduce o/l through LDS -> write out directly.
//    Removes 16MB Opart + 1MB lpart round-trip and one dispatch.
//  - QK^T uses mfma_f32_16x16x16bf16_1k (K=16 == d_head, no zero-padded half):
//    halves QK matrix cycles, -24 VGPR (qfs/kf 4-short frags), halves K-frag
//    load bytes. Guarded; falls back to v13's zero-padded 16x16x32 path.
//  - __launch_bounds__(512,4) pins <=128 VGPR so attn keeps 4 waves/SIMD.
// Math identical to v13 (extra K=32 half was exact zeros; reduction order of
// the 8 key-splits matches old combine's s-ascending order).
// ---------------------------------------------------------------------------

typedef __attribute__((ext_vector_type(4))) float    f32x4;
typedef __attribute__((ext_vector_type(8))) short    s16x8;
typedef __attribute__((ext_vector_type(4))) short    s16x4;
typedef __attribute__((ext_vector_type(8))) __bf16   bf16x8;
typedef __attribute__((ext_vector_type(4))) unsigned u32x4;

union FragAB { s16x8 s; bf16x8 b; u32x4 u; };

__device__ __forceinline__ short f2bf(float f) {
    unsigned u = __float_as_uint(f);
    u += 0x7fff + ((u >> 16) & 1);          // RNE
    return (short)(u >> 16);
}

__device__ __forceinline__ unsigned pkbf(float a, float b) {
    float2 f2; f2.x = a; f2.y = b;
    __hip_bfloat162 h = __float22bfloat162_rn(f2);   // v_cvt_pk_bf16_f32
    unsigned r;
    __builtin_memcpy(&r, &h, 4);                      // lo = a, hi = b
    return r;
}

#if __has_builtin(__builtin_amdgcn_exp2f)
  #define FASTEXP(x) __builtin_amdgcn_exp2f(x)
  #define QK_SCALE 0.12751744154070513f   // (1/sqrt(128)) * log2(e)
#else
  #define FASTEXP(x) __expf(x)
  #define QK_SCALE 0.08838834764831845f   // 1/sqrt(128)
#endif

#if __has_builtin(__builtin_amdgcn_mfma_f32_16x16x16bf16_1k)
  #define HAVE_MFMA16 1
#else
  #define HAVE_MFMA16 0
#endif

// ---------------------------------------------------------------------------
// QKV: MFMA GEMM. Q -> qT[h][n][16] (scaled). K,V -> interleaved kv buffer:
// kv[(h*64+T)*2048 + key_local*16 + d]                  (K region, 2KB/tile)
// kv[(h*64+T)*2048 + 1024 + d*64 + c*32 + qp*8 + jj]    (V region, permuted:
//   key = T*64 + c*32 + (jj>=4?16:0) + qp*4 + (jj&3) -- PV B-frag slot order)
// ---------------------------------------------------------------------------
__global__ __launch_bounds__(256) void qkv_kernel(
    const float* __restrict__ x, const float* __restrict__ w,
    short* __restrict__ qT, short* __restrict__ kv)
{
    __shared__ __align__(16) short xT[4][16][136];   // [wave][n][c], pad 8
    const int wv   = threadIdx.x >> 6;
    const int lane = threadIdx.x & 63;
    const int colL = lane & 15, quad = lane >> 4;
    const int n0 = blockIdx.x * 64 + wv * 16;
    const int oq = blockIdx.y;                        // 0..3

    #pragma unroll
    for (int rr = 0; rr < 4; ++rr) {
        int c  = rr * 32 + (lane >> 1);
        int nh = (lane & 1) * 8;
        f32x4 a = *(const f32x4*)&x[c * 4096 + n0 + nh];
        f32x4 b = *(const f32x4*)&x[c * 4096 + n0 + nh + 4];
        #pragma unroll
        for (int t = 0; t < 4; ++t) {
            xT[wv][nh + t][c]     = f2bf(a[t]);
            xT[wv][nh + 4 + t][c] = f2bf(b[t]);
        }
    }
    __syncthreads();

    FragAB xb[4];
    #pragma unroll
    for (int ks = 0; ks < 4; ++ks)
        xb[ks].s = *(const s16x8*)&xT[wv][colL][ks * 32 + quad * 8];

    const int T    = blockIdx.x;
    const int wloc = wv * 16 + colL;          // key_local = n & 63
    const int cc   = wloc >> 5;
    const int bb   = (wloc >> 4) & 1;
    const int qp   = (wloc >> 2) & 3;
    const int jj   = bb * 4 + (wloc & 3);

    #pragma unroll
    for (int i = 0; i < 6; ++i) {
        const int otg  = oq * 6 + i;
        const int ob   = otg * 16;
        const int h    = otg / 3;
        const int kind = otg % 3;             // 0=q, 1=k, 2=v
        f32x4 acc = {0.f, 0.f, 0.f, 0.f};
        #pragma unroll
        for (int ks = 0; ks < 4; ++ks) {
            f32x4 wa0 = *(const f32x4*)&w[(ob + colL) * 128 + ks * 32 + quad * 8];
            f32x4 wa1 = *(const f32x4*)&w[(ob + colL) * 128 + ks * 32 + quad * 8 + 4];
            FragAB wa;
            #pragma unroll
            for (int t = 0; t < 4; ++t) {
                wa.s[t]     = f2bf(wa0[t]);
                wa.s[t + 4] = f2bf(wa1[t]);
            }
            acc = __builtin_amdgcn_mfma_f32_16x16x32_bf16(wa.b, xb[ks].b, acc, 0, 0, 0);
        }
        // C: row = o_local = quad*4+r, col = n
        if (kind == 0) {
            s16x4 pk;
            #pragma unroll
            for (int r = 0; r < 4; ++r) pk[r] = f2bf(acc[r] * QK_SCALE);
            *(s16x4*)&qT[(h * 4096 + n0 + colL) * 16 + quad * 4] = pk;
        } else if (kind == 1) {
            s16x4 pk;
            #pragma unroll
            for (int r = 0; r < 4; ++r) pk[r] = f2bf(acc[r]);
            *(s16x4*)&kv[(h * 64 + T) * 2048 + wloc * 16 + quad * 4] = pk;
        } else {
            #pragma unroll
            for (int r = 0; r < 4; ++r) {
                int d = quad * 4 + r;
                kv[(h * 64 + T) * 2048 + 1024 + d * 64 + cc * 32 + qp * 8 + jj] = f2bf(acc[r]);
            }
        }
    }
}

// ---------------------------------------------------------------------------
// Attention v14: block = 64 q rows of one head, 8 waves split keys 8-ways
// (8 kt of 64 keys each). Per kt per u: 4 QK MFMA (K=16) -> 16 trans exp ->
// 8 cvt_pk -> 2 PV + 2 l MFMA. Epilogue: LDS 8-way reduce of o/l, divide,
// coalesced float2 stores to out.
// ---------------------------------------------------------------------------
__global__ __launch_bounds__(512, 4) void attn_kernel(
    const short* __restrict__ qT, const short* __restrict__ kv,
    float* __restrict__ out)
{
    __shared__ float lds_o[8][16][66];   // [wave][d][q], q-pad to 66 (8B align)
    __shared__ float lds_l[8][64];

    const int wv   = threadIdx.x >> 6;   // 0..7 = key-split index
    const int lane = threadIdx.x & 63;
    const int colL = lane & 15, quad = lane >> 4;

    const int h     = blockIdx.x >> 6;   // 0..7
    const int qb    = blockIdx.x & 63;   // 0..63
    const int qbase = qb * 64;

#if HAVE_MFMA16
    s16x4 qfs[4];                         // B-frags: Q^T[d][q], K=16 exact
    #pragma unroll
    for (int u = 0; u < 4; ++u)
        qfs[u] = *(const s16x4*)&qT[(h * 4096 + qbase + u * 16 + colL) * 16 + quad * 4];
#else
    FragAB qfs[4];                        // zero-padded K=32 fallback
    #pragma unroll
    for (int u = 0; u < 4; ++u) {
        qfs[u].s = 0;
        if (quad < 2)
            qfs[u].s = *(const s16x8*)&qT[(h * 4096 + qbase + u * 16 + colL) * 16 + quad * 8];
    }
#endif

    FragAB ones;                          // all-ones bf16 A-frag (l = colsum)
    #pragma unroll
    for (int j = 0; j < 8; ++j) ones.s[j] = (short)0x3F80;

    f32x4 o[4], ol[4];
    #pragma unroll
    for (int u = 0; u < 4; ++u) {
        o[u]  = (f32x4){0.f, 0.f, 0.f, 0.f};
        ol[u] = (f32x4){0.f, 0.f, 0.f, 0.f};
    }

    // loop-invariant lane offsets (shorts)
    const int voffK16 = colL * 16 + quad * 4;        // + t*256 (K=16 frag)
    const int voffK32 = colL * 16 + quad * 8;        // + t*256 (K=32 frag)
    const int voffV   = 1024 + colL * 64 + quad * 8; // + c*32
    (void)voffK32; (void)voffK16;

    const short* kvb = kv + (h * 64 + wv * 8) * 2048;

    #pragma unroll
    for (int kt = 0; kt < 8; ++kt) {
#if HAVE_MFMA16
        s16x4 kf[4];
        #pragma unroll
        for (int t = 0; t < 4; ++t)
            kf[t] = *(const s16x4*)&kvb[voffK16 + t * 256];
#else
        FragAB kf[4];
        #pragma unroll
        for (int t = 0; t < 4; ++t)
            kf[t].s = *(const s16x8*)&kvb[voffK32 + t * 256];
#endif
        FragAB vf[2];
        #pragma unroll
        for (int c = 0; c < 2; ++c)
            vf[c].s = *(const s16x8*)&kvb[voffV + c * 32];
        kvb += 2048;

        #pragma unroll
        for (int u = 0; u < 4; ++u) {
            f32x4 st[4];
            #pragma unroll
            for (int t = 0; t < 4; ++t) {
                f32x4 z = {0.f, 0.f, 0.f, 0.f};
#if HAVE_MFMA16
                st[t] = __builtin_amdgcn_mfma_f32_16x16x16bf16_1k(kf[t], qfs[u], z, 0, 0, 0);
#else
                st[t] = __builtin_amdgcn_mfma_f32_16x16x32_bf16(kf[t].b, qfs[u].b, z, 0, 0, 0);
#endif
            }
            FragAB p0, p1;
            #pragma unroll
            for (int t = 0; t < 2; ++t) {
                p0.u[t * 2 + 0] = pkbf(FASTEXP(st[t][0]), FASTEXP(st[t][1]));
                p0.u[t * 2 + 1] = pkbf(FASTEXP(st[t][2]), FASTEXP(st[t][3]));
                p1.u[t * 2 + 0] = pkbf(FASTEXP(st[t + 2][0]), FASTEXP(st[t + 2][1]));
                p1.u[t * 2 + 1] = pkbf(FASTEXP(st[t + 2][2]), FASTEXP(st[t + 2][3]));
            }
            o[u]  = __builtin_amdgcn_mfma_f32_16x16x32_bf16(vf[0].b, p0.b, o[u],  0, 0, 0);
            ol[u] = __builtin_amdgcn_mfma_f32_16x16x32_bf16(ones.b,  p0.b, ol[u], 0, 0, 0);
            o[u]  = __builtin_amdgcn_mfma_f32_16x16x32_bf16(vf[1].b, p1.b, o[u],  0, 0, 0);
            ol[u] = __builtin_amdgcn_mfma_f32_16x16x32_bf16(ones.b,  p1.b, ol[u], 0, 0, 0);
        }
    }

    // ---- in-block 8-way key-split reduction via LDS ----
    // o[u][r] = O_part[d = quad*4+r][q = u*16+colL]; ol[u][0] = l_part[q].
    #pragma unroll
    for (int u = 0; u < 4; ++u) {
        #pragma unroll
        for (int r = 0; r < 4; ++r)
            lds_o[wv][quad * 4 + r][u * 16 + colL] = o[u][r];
    }
    if (quad == 0) {
        #pragma unroll
        for (int u = 0; u < 4; ++u)
            lds_l[wv][u * 16 + colL] = ol[u][0];
    }
    __syncthreads();

    // 512 threads: thread -> (d, q-pair). Coalesced 256B-per-row out stores.
    const int d  = threadIdx.x >> 5;          // 0..15
    const int q2 = (threadIdx.x & 31) * 2;    // 0,2,..,62
    float ox = 0.f, oy = 0.f, lx = 0.f, ly = 0.f;
    #pragma unroll
    for (int s = 0; s < 8; ++s) {             // same order as old combine loop
        float2 ov = *(const float2*)&lds_o[s][d][q2];
        float2 lv = *(const float2*)&lds_l[s][q2];
        ox += ov.x; oy += ov.y;
        lx += lv.x; ly += lv.y;
    }
    float2 res;
    res.x = ox / lx;
    res.y = oy / ly;
    *(float2*)&out[(h * 16 + d) * 4096 + qbase + q2] = res;
}

// ---------------------------------------------------------------------------
extern "C" void kernel_launch(void* const* d_in, const int* in_sizes, int n_in,
                              void* d_out, int out_size, void* d_ws, size_t ws_size,
                              hipStream_t stream) {
    const float* x = (const float*)d_in[0];   // (128, 4096) fp32
    const float* w = (const float*)d_in[1];   // (384, 128) fp32
    float* out = (float*)d_out;               // (128, 4096) fp32

    char* ws = (char*)d_ws;
    short* qT = (short*)ws;                          // 1 MB
    short* kv = (short*)(ws + (1u << 20));           // 2 MB interleaved K|V

    dim3 gq(64, 4);
    qkv_kernel<<<gq, 256, 0, stream>>>(x, w, qT, kv);
    attn_kernel<<<512, 512, 0, stream>>>(qT, kv, out);
}